// Round 4
// baseline (1243.957 us; speedup 1.0000x reference)
//
#include <hip/hip_runtime.h>
#include <hip/hip_bf16.h>

typedef unsigned short u16;
typedef __bf16 bf16x8 __attribute__((ext_vector_type(8)));
typedef unsigned short ushort8v __attribute__((ext_vector_type(8)));
typedef float f32x4 __attribute__((ext_vector_type(4)));

#define B_ 4
#define T_ 2048
#define C_ 2048
#define H_ 32
#define S_ 64

__device__ __forceinline__ u16 f2bf(float x) {
  unsigned int u = __float_as_uint(x);
  unsigned int r = (u + 0x7fffu + ((u >> 16) & 1u)) >> 16;
  return (u16)r;
}
__device__ __forceinline__ float bf2f(u16 x) {
  return __uint_as_float(((unsigned int)x) << 16);
}
__device__ __forceinline__ void gload_lds16(const void* g, void* l) {
  __builtin_amdgcn_global_load_lds(
      (const __attribute__((address_space(1))) void*)g,
      (__attribute__((address_space(3))) void*)l, 16, 0, 0);
}

// ---------------- mix + cast to bf16 ----------------
__global__ __launch_bounds__(256) void mix_cast_kernel(
    const float* __restrict__ hidden, const float* __restrict__ mixp,
    u16* __restrict__ out) {
  int idx = blockIdx.x * 256 + threadIdx.x;  // float4 index, total B*T*C/4
  int c4 = idx & 511;                        // C/4 = 512
  int bt = idx >> 9;
  int t = bt & (T_ - 1);
  float4 h = reinterpret_cast<const float4*>(hidden)[idx];
  float4 m = reinterpret_cast<const float4*>(mixp)[c4];
  float4 sh = make_float4(0.f, 0.f, 0.f, 0.f);
  if (t != 0) sh = reinterpret_cast<const float4*>(hidden)[idx - 512];
  ushort4 o;
  o.x = f2bf(h.x * m.x + sh.x * (1.f - m.x));
  o.y = f2bf(h.y * m.y + sh.y * (1.f - m.y));
  o.z = f2bf(h.z * m.z + sh.z * (1.f - m.z));
  o.w = f2bf(h.w * m.w + sh.w * (1.f - m.w));
  reinterpret_cast<ushort4*>(out)[idx] = o;
}

// ---------------- fp32 -> bf16 weight cast ----------------
__global__ __launch_bounds__(256) void conv_bf16_kernel(
    const float* __restrict__ in, u16* __restrict__ out, int n4) {
  int i = blockIdx.x * 256 + threadIdx.x;
  if (i >= n4) return;
  float4 v = reinterpret_cast<const float4*>(in)[i];
  ushort4 o;
  o.x = f2bf(v.x); o.y = f2bf(v.y); o.z = f2bf(v.z); o.w = f2bf(v.w);
  reinterpret_cast<ushort4*>(out)[i] = o;
}

// ---------------- bf16 GEMM: C[M,N] = A[M,K] * B[N,K]^T ----------------
template <typename OT>
__global__ __launch_bounds__(256) void gemm_bt(
    const u16* __restrict__ A, const u16* __restrict__ Bm,
    OT* __restrict__ C, int M, int N, int K) {
  __shared__ u16 As[128 * 64];
  __shared__ u16 Bs[128 * 64];
  int tid = threadIdx.x, lane = tid & 63, wid = tid >> 6;
  int nbn = N >> 7;
  int nwg = gridDim.x;
  int bid = blockIdx.x;
  int cpx = nwg >> 3;  // grid is a multiple of 8 here
  int swz = (bid & 7) * cpx + (bid >> 3);
  int bm = swz / nbn, bn = swz % nbn;
  int wr = wid >> 1, wc = wid & 1;

  f32x4 acc[4][4];
#pragma unroll
  for (int m = 0; m < 4; m++)
#pragma unroll
    for (int n = 0; n < 4; n++) acc[m][n] = (f32x4){0.f, 0.f, 0.f, 0.f};

  int row_in = lane >> 3;  // 0..7
  int col8 = lane & 7;     // 0..7 (x8 bf16 = 16B)
  const u16* Abase = A + ((size_t)(bm * 128 + wid * 32 + row_in)) * K + col8 * 8;
  const u16* Bbase = Bm + ((size_t)(bn * 128 + wid * 32 + row_in)) * K + col8 * 8;

  for (int kt = 0; kt < K; kt += 64) {
#pragma unroll
    for (int it = 0; it < 4; ++it) {
      gload_lds16(Abase + (size_t)(it * 8) * K + kt, &As[(wid * 32 + it * 8) * 64]);
      gload_lds16(Bbase + (size_t)(it * 8) * K + kt, &Bs[(wid * 32 + it * 8) * 64]);
    }
    __syncthreads();
#pragma unroll
    for (int kk = 0; kk < 2; ++kk) {
      int koff = kk * 32 + (lane >> 4) * 8;
      bf16x8 af[4], bfr[4];
      int rowa = wr * 64 + (lane & 15);
      int rowb = wc * 64 + (lane & 15);
#pragma unroll
      for (int m = 0; m < 4; m++) {
        ushort8v t8 = *reinterpret_cast<const ushort8v*>(&As[(rowa + m * 16) * 64 + koff]);
        af[m] = __builtin_bit_cast(bf16x8, t8);
      }
#pragma unroll
      for (int n = 0; n < 4; n++) {
        ushort8v t8 = *reinterpret_cast<const ushort8v*>(&Bs[(rowb + n * 16) * 64 + koff]);
        bfr[n] = __builtin_bit_cast(bf16x8, t8);
      }
#pragma unroll
      for (int m = 0; m < 4; m++)
#pragma unroll
        for (int n = 0; n < 4; n++)
          acc[m][n] = __builtin_amdgcn_mfma_f32_16x16x32_bf16(af[m], bfr[n], acc[m][n], 0, 0, 0);
    }
    __syncthreads();
  }

  int crow0 = bm * 128 + wr * 64 + (lane >> 4) * 4;
  int ccol = bn * 128 + wc * 64 + (lane & 15);
#pragma unroll
  for (int m = 0; m < 4; m++) {
#pragma unroll
    for (int q = 0; q < 4; q++) {
      OT* cp = C + (size_t)(crow0 + m * 16 + q) * N + ccol;
#pragma unroll
      for (int n = 0; n < 4; n++) {
        if constexpr (sizeof(OT) == 2)
          cp[n * 16] = (OT)f2bf(acc[m][n][q]);
        else
          cp[n * 16] = (OT)acc[m][n][q];
      }
    }
  }
}

// ---------------- scan phase 1 (MFMA): S_c[s,d] = sum_i w_s^{L-1-i} k_i[s] v_i[d] ----------------
// One wave per (b,h,chunk); A[s][i] = k_i[s]*w_s^{L-1-i} (bf16, bounded), B = V^T[d][i].
template <int CHL>
__global__ __launch_bounds__(128) void scan_phase1_mfma(
    const u16* __restrict__ Kb, const u16* __restrict__ Vb,
    const float* __restrict__ td, float* __restrict__ chunks) {
  constexpr int NCH = T_ / CHL;
  constexpr int LDW = CHL + 8;  // padded row (elements) -> 144B rows, 16B aligned
  __shared__ u16 Ash[2][64 * LDW];
  __shared__ u16 Vsh[2][64 * LDW];
  int lane = threadIdx.x & 63, wib = threadIdx.x >> 6;
  int gw = blockIdx.x * 2 + wib;
  int c = gw & (NCH - 1), bh = gw / NCH;
  int h = bh & 31, b = bh >> 5;

  size_t base = ((size_t)b * T_ + (size_t)c * CHL) * C_ + h * 64 + lane;
  const u16* Kp = Kb + base;  // k[i][s=lane] at +i*C_
  const u16* Vp = Vb + base;  // v[i][d=lane]

  // A staging (lane = s): descending i, p = w^{L-1-i} built by p *= w (decay only; underflow->0 is correct)
  {
    float w = __expf(-__expf(td[h * 64 + lane]));
    u16* Arow = &Ash[wib][lane * LDW];
    float p = 1.f;
#pragma unroll
    for (int i4 = CHL - 4; i4 >= 0; i4 -= 4) {
      float a3 = bf2f(Kp[(size_t)(i4 + 3) * C_]) * p; p *= w;
      float a2 = bf2f(Kp[(size_t)(i4 + 2) * C_]) * p; p *= w;
      float a1 = bf2f(Kp[(size_t)(i4 + 1) * C_]) * p; p *= w;
      float a0 = bf2f(Kp[(size_t)(i4 + 0) * C_]) * p; p *= w;
      ushort4 pk;
      pk.x = f2bf(a0); pk.y = f2bf(a1); pk.z = f2bf(a2); pk.w = f2bf(a3);
      *reinterpret_cast<ushort4*>(&Arow[i4]) = pk;
    }
  }
  // V^T staging (lane = d): Vsh[d][i] = v[i][d]
  {
    u16* Vrow = &Vsh[wib][lane * LDW];
#pragma unroll
    for (int i4 = 0; i4 < CHL; i4 += 4) {
      ushort4 pk;
      pk.x = Vp[(size_t)(i4 + 0) * C_];
      pk.y = Vp[(size_t)(i4 + 1) * C_];
      pk.z = Vp[(size_t)(i4 + 2) * C_];
      pk.w = Vp[(size_t)(i4 + 3) * C_];
      *reinterpret_cast<ushort4*>(&Vrow[i4]) = pk;
    }
  }
  // wave-private LDS: no barrier needed; compiler orders ds ops.

  f32x4 acc[4][4];
#pragma unroll
  for (int m = 0; m < 4; m++)
#pragma unroll
    for (int n = 0; n < 4; n++) acc[m][n] = (f32x4){0.f, 0.f, 0.f, 0.f};

#pragma unroll
  for (int kb = 0; kb < CHL / 32; kb++) {
    int ko = kb * 32 + (lane >> 4) * 8;
    bf16x8 Af[4], Bf[4];
#pragma unroll
    for (int m = 0; m < 4; m++) {
      ushort8v t8 = *reinterpret_cast<const ushort8v*>(&Ash[wib][(m * 16 + (lane & 15)) * LDW + ko]);
      Af[m] = __builtin_bit_cast(bf16x8, t8);
    }
#pragma unroll
    for (int n = 0; n < 4; n++) {
      ushort8v t8 = *reinterpret_cast<const ushort8v*>(&Vsh[wib][(n * 16 + (lane & 15)) * LDW + ko]);
      Bf[n] = __builtin_bit_cast(bf16x8, t8);
    }
#pragma unroll
    for (int m = 0; m < 4; m++)
#pragma unroll
      for (int n = 0; n < 4; n++)
        acc[m][n] = __builtin_amdgcn_mfma_f32_16x16x32_bf16(Af[m], Bf[n], acc[m][n], 0, 0, 0);
  }

  float* outp = chunks + (((size_t)c * B_ + b) * H_ + h) * 4096;
  int r0 = (lane >> 4) * 4, c0 = lane & 15;
#pragma unroll
  for (int m = 0; m < 4; m++)
#pragma unroll
    for (int n = 0; n < 4; n++)
#pragma unroll
      for (int q = 0; q < 4; q++)
        outp[(size_t)(m * 16 + r0 + q) * 64 + n * 16 + c0] = acc[m][n][q];
}

// ---------------- scan phase 1 (scalar, fallback for CHL=128) ----------------
template <int NCH, int CHL>
__global__ __launch_bounds__(256) void scan_phase1(
    const u16* __restrict__ Kb, const u16* __restrict__ Vb,
    const float* __restrict__ td, float* __restrict__ chunks) {
  int lane = threadIdx.x & 63;
  int gw = (blockIdx.x * 256 + threadIdx.x) >> 6;
  int c = gw & (NCH - 1), bh = gw / NCH;
  int h = bh & 31, b = bh >> 5;
  const float* tdh = td + h * 64;
  float wreg[64];
#pragma unroll
  for (int s = 0; s < 64; s++) wreg[s] = __expf(-__expf(tdh[s]));
  float st[64];
#pragma unroll
  for (int s = 0; s < 64; s++) st[s] = 0.f;
  size_t base = ((size_t)b * T_ + (size_t)c * CHL) * C_ + h * 64 + lane;
  const u16* Kp = Kb + base;
  const u16* Vp = Vb + base;
  for (int t = 0; t < CHL; t++) {
    float kcur = bf2f(Kp[(size_t)t * C_]), vcur = bf2f(Vp[(size_t)t * C_]);
#pragma unroll
    for (int s = 0; s < 64; s++) {
      float ks = __shfl(kcur, s);
      st[s] = fmaf(wreg[s], st[s], ks * vcur);
    }
  }
  float* outp = chunks + (((size_t)c * B_ + b) * H_ + h) * 4096 + lane;
#pragma unroll
  for (int s = 0; s < 64; s++) outp[s * 64] = st[s];
}

// ---------------- scan phase 2: propagate boundary states across chunks ----------------
template <int NCH, int CHL>
__global__ __launch_bounds__(256) void scan_phase2(
    const float* __restrict__ st0, const float* __restrict__ td,
    float* __restrict__ chunks, float* __restrict__ state_out) {
  int idx = blockIdx.x * 256 + threadIdx.x;  // < 524288 over [b][h][s][d]
  int h = (idx >> 12) & 31;
  int s = (idx >> 6) & 63;
  float wL = __expf(-(float)CHL * __expf(td[h * 64 + s]));  // w^CHL
  float st = st0[idx];
#pragma unroll
  for (int cc = 0; cc < NCH; cc++) {
    size_t off = (size_t)cc * 524288 + idx;
    float sc = chunks[off];
    chunks[off] = st;  // boundary state at START of chunk cc
    st = fmaf(wL, st, sc);
  }
  state_out[idx] = st;
}

// ---------------- scan phase 3 (LDS-broadcast) + fused groupnorm/ln/silu -> bf16 ----------------
template <int CHL>
__global__ __launch_bounds__(256) void scan_phase3_lds(
    const u16* __restrict__ Rb, const u16* __restrict__ Kb,
    const u16* __restrict__ Vb, const float* __restrict__ td,
    const float* __restrict__ tf, const float* __restrict__ chunks,
    const u16* __restrict__ Gb, const float* __restrict__ lnw,
    const float* __restrict__ lnb, u16* __restrict__ Y) {
  constexpr int NCH = T_ / CHL;
  constexpr int TS = 8;  // timesteps per LDS sub-tile
  __shared__ float4 tile[4][TS * 64];  // per-wave private: (k, r, w, 0) per (t,s)
  int lane = threadIdx.x & 63, wib = threadIdx.x >> 6;
  int gw = blockIdx.x * 4 + wib;
  int c = gw & (NCH - 1), bh = gw / NCH;
  int h = bh & 31, b = bh >> 5;

  float w_lane = __expf(-__expf(td[h * 64 + lane]));
  float u_lane = tf[h * 64 + lane];
  float lw = lnw[h * 64 + lane];
  float lb = lnb[h * 64 + lane];

  float st[64];
  const float* cp = chunks + (((size_t)c * B_ + b) * H_ + h) * 4096 + lane;
#pragma unroll
  for (int s = 0; s < 64; s++) st[s] = cp[s * 64];

  size_t base = ((size_t)b * T_ + (size_t)c * CHL) * C_ + h * 64 + lane;
  const u16* Rp = Rb + base;
  const u16* Kp = Kb + base;
  const u16* Vp = Vb + base;
  const u16* Gp = Gb + base;
  u16* Yp = Y + base;

  for (int sub = 0; sub < CHL / TS; sub++) {
    // stage (k, r, w) for TS timesteps; lane = s (coalesced global reads)
#pragma unroll
    for (int tt = 0; tt < TS; tt++) {
      size_t t = (size_t)(sub * TS + tt);
      tile[wib][tt * 64 + lane] =
          make_float4(bf2f(Kp[t * C_]), bf2f(Rp[t * C_]), w_lane, 0.f);
    }
#pragma unroll
    for (int tt = 0; tt < TS; tt++) {
      size_t t = (size_t)(sub * TS + tt);
      float vcur = bf2f(Vp[t * C_]);
      float4 own = tile[wib][tt * 64 + lane];  // (k,r) at s=lane for diag term
      float p = own.y * u_lane * own.x;
#pragma unroll
      for (int off = 32; off >= 1; off >>= 1) p += __shfl_xor(p, off);
      float a0 = 0.f, a1 = 0.f, a2 = 0.f, a3 = 0.f;
      const float4* tp = &tile[wib][tt * 64];
#pragma unroll
      for (int s = 0; s < 64; s += 4) {
        float4 e0 = tp[s + 0];  // uniform address -> HW broadcast
        float4 e1 = tp[s + 1];
        float4 e2 = tp[s + 2];
        float4 e3 = tp[s + 3];
        a0 = fmaf(e0.y, st[s + 0], a0); st[s + 0] = fmaf(e0.z, st[s + 0], e0.x * vcur);
        a1 = fmaf(e1.y, st[s + 1], a1); st[s + 1] = fmaf(e1.z, st[s + 1], e1.x * vcur);
        a2 = fmaf(e2.y, st[s + 2], a2); st[s + 2] = fmaf(e2.z, st[s + 2], e2.x * vcur);
        a3 = fmaf(e3.y, st[s + 3], a3); st[s + 3] = fmaf(e3.z, st[s + 3], e3.x * vcur);
      }
      float o = fmaf(p, vcur, (a0 + a1) + (a2 + a3));
      // fused groupnorm over the wave's 64 lanes (= one (bt,h) group)
      float x = o * 0.125f;
      float sum = x;
#pragma unroll
      for (int off = 32; off >= 1; off >>= 1) sum += __shfl_xor(sum, off);
      float mean = sum * (1.f / 64.f);
      float dd = x - mean;
      float v2 = dd * dd;
#pragma unroll
      for (int off = 32; off >= 1; off >>= 1) v2 += __shfl_xor(v2, off);
      float var = v2 * (1.f / 64.f);
      float xn = dd * rsqrtf(var + 1e-5f);
      float g = bf2f(Gp[t * C_]);
      float sg = g / (1.f + __expf(-g));
      Yp[t * C_] = f2bf((xn * lw + lb) * sg);
    }
  }
}

extern "C" void kernel_launch(void* const* d_in, const int* in_sizes, int n_in,
                              void* d_out, int out_size, void* d_ws, size_t ws_size,
                              hipStream_t stream) {
  const float* hidden = (const float*)d_in[0];
  const float* state0 = (const float*)d_in[1];
  const float* td = (const float*)d_in[2];
  const float* tf = (const float*)d_in[3];
  const float* mk = (const float*)d_in[4];
  const float* mv = (const float*)d_in[5];
  const float* mr = (const float*)d_in[6];
  const float* mg = (const float*)d_in[7];
  const float* kw = (const float*)d_in[8];
  const float* vw = (const float*)d_in[9];
  const float* rw = (const float*)d_in[10];
  const float* gw = (const float*)d_in[11];
  const float* ow = (const float*)d_in[12];
  const float* lnw = (const float*)d_in[13];
  const float* lnb = (const float*)d_in[14];

  float* out = (float*)d_out;
  float* state_f = out + (size_t)B_ * T_ * C_;

  // workspace layout
  char* ws = (char*)d_ws;
  u16* mixA = (u16*)ws;    ws += (size_t)B_ * T_ * C_ * 2;  // 33.5MB
  u16* wb = (u16*)ws;      ws += (size_t)C_ * C_ * 2;       // 8.4MB
  u16* rb = (u16*)ws;      ws += (size_t)B_ * T_ * C_ * 2;
  u16* kb = (u16*)ws;      ws += (size_t)B_ * T_ * C_ * 2;
  u16* vb = (u16*)ws;      ws += (size_t)B_ * T_ * C_ * 2;
  u16* gb = (u16*)ws;      ws += (size_t)B_ * T_ * C_ * 2;
  float* chunks = (float*)ws;
  size_t fixed = (size_t)(ws - (char*)d_ws);
  size_t chunks32 = (size_t)32 * B_ * H_ * S_ * S_ * 4;  // 67.1MB
  bool use32 = (ws_size >= fixed + chunks32);

  dim3 blk(256);
  int mixGrid = (B_ * T_ * C_ / 4) / 256;       // 16384
  int convN4 = C_ * C_ / 4;                     // 1048576
  int convGrid = convN4 / 256;                  // 4096
  int gemmGrid = (B_ * T_ / 128) * (C_ / 128);  // 1024

  // receptance
  mix_cast_kernel<<<mixGrid, blk, 0, stream>>>(hidden, mr, mixA);
  conv_bf16_kernel<<<convGrid, blk, 0, stream>>>(rw, wb, convN4);
  gemm_bt<u16><<<gemmGrid, blk, 0, stream>>>(mixA, wb, rb, B_ * T_, C_, C_);
  // key
  mix_cast_kernel<<<mixGrid, blk, 0, stream>>>(hidden, mk, mixA);
  conv_bf16_kernel<<<convGrid, blk, 0, stream>>>(kw, wb, convN4);
  gemm_bt<u16><<<gemmGrid, blk, 0, stream>>>(mixA, wb, kb, B_ * T_, C_, C_);
  // value
  mix_cast_kernel<<<mixGrid, blk, 0, stream>>>(hidden, mv, mixA);
  conv_bf16_kernel<<<convGrid, blk, 0, stream>>>(vw, wb, convN4);
  gemm_bt<u16><<<gemmGrid, blk, 0, stream>>>(mixA, wb, vb, B_ * T_, C_, C_);
  // gate
  mix_cast_kernel<<<mixGrid, blk, 0, stream>>>(hidden, mg, mixA);
  conv_bf16_kernel<<<convGrid, blk, 0, stream>>>(gw, wb, convN4);
  gemm_bt<u16><<<gemmGrid, blk, 0, stream>>>(mixA, wb, gb, B_ * T_, C_, C_);

  // scan
  if (use32) {
    scan_phase1_mfma<64><<<(B_ * H_ * 32) / 2, dim3(128), 0, stream>>>(kb, vb, td, chunks);
    scan_phase2<32, 64><<<2048, blk, 0, stream>>>(state0, td, chunks, state_f);
    scan_phase3_lds<64><<<(B_ * H_ * 32) / 4, blk, 0, stream>>>(rb, kb, vb, td, tf, chunks, gb, lnw, lnb, mixA);
  } else {
    scan_phase1<16, 128><<<(B_ * H_ * 16) / 4, blk, 0, stream>>>(kb, vb, td, chunks);
    scan_phase2<16, 128><<<2048, blk, 0, stream>>>(state0, td, chunks, state_f);
    scan_phase3_lds<128><<<(B_ * H_ * 16) / 4, blk, 0, stream>>>(rb, kb, vb, td, tf, chunks, gb, lnw, lnb, mixA);
  }

  // output projection -> d_out
  conv_bf16_kernel<<<convGrid, blk, 0, stream>>>(ow, wb, convN4);
  gemm_bt<float><<<gemmGrid, blk, 0, stream>>>(mixA, wb, out, B_ * T_, C_, C_);
}

// Round 5
// 792.015 us; speedup vs baseline: 1.5706x; 1.5706x over previous
//
#include <hip/hip_runtime.h>
#include <hip/hip_bf16.h>

typedef unsigned short u16;
typedef __bf16 bf16x8 __attribute__((ext_vector_type(8)));
typedef unsigned short ushort8v __attribute__((ext_vector_type(8)));
typedef float f32x4 __attribute__((ext_vector_type(4)));
typedef float f32x8 __attribute__((ext_vector_type(8)));

#define B_ 4
#define T_ 2048
#define C_ 2048
#define H_ 32
#define S_ 64

__device__ __forceinline__ u16 f2bf(float x) {
  unsigned int u = __float_as_uint(x);
  unsigned int r = (u + 0x7fffu + ((u >> 16) & 1u)) >> 16;
  return (u16)r;
}
__device__ __forceinline__ float bf2f(u16 x) {
  return __uint_as_float(((unsigned int)x) << 16);
}
__device__ __forceinline__ void gload_lds16(const void* g, void* l) {
  __builtin_amdgcn_global_load_lds(
      (const __attribute__((address_space(1))) void*)g,
      (__attribute__((address_space(3))) void*)l, 16, 0, 0);
}

// ---------------- mix + cast to bf16 ----------------
__global__ __launch_bounds__(256) void mix_cast_kernel(
    const float* __restrict__ hidden, const float* __restrict__ mixp,
    u16* __restrict__ out) {
  int idx = blockIdx.x * 256 + threadIdx.x;
  int c4 = idx & 511;
  int bt = idx >> 9;
  int t = bt & (T_ - 1);
  float4 h = reinterpret_cast<const float4*>(hidden)[idx];
  float4 m = reinterpret_cast<const float4*>(mixp)[c4];
  float4 sh = make_float4(0.f, 0.f, 0.f, 0.f);
  if (t != 0) sh = reinterpret_cast<const float4*>(hidden)[idx - 512];
  ushort4 o;
  o.x = f2bf(h.x * m.x + sh.x * (1.f - m.x));
  o.y = f2bf(h.y * m.y + sh.y * (1.f - m.y));
  o.z = f2bf(h.z * m.z + sh.z * (1.f - m.z));
  o.w = f2bf(h.w * m.w + sh.w * (1.f - m.w));
  reinterpret_cast<ushort4*>(out)[idx] = o;
}

// ---------------- fp32 -> bf16 weight cast ----------------
__global__ __launch_bounds__(256) void conv_bf16_kernel(
    const float* __restrict__ in, u16* __restrict__ out, int n4) {
  int i = blockIdx.x * 256 + threadIdx.x;
  if (i >= n4) return;
  float4 v = reinterpret_cast<const float4*>(in)[i];
  ushort4 o;
  o.x = f2bf(v.x); o.y = f2bf(v.y); o.z = f2bf(v.z); o.w = f2bf(v.w);
  reinterpret_cast<ushort4*>(out)[i] = o;
}

// ---------------- bf16 GEMM: C[M,N] = A[M,K] * B[N,K]^T ----------------
template <typename OT>
__global__ __launch_bounds__(256) void gemm_bt(
    const u16* __restrict__ A, const u16* __restrict__ Bm,
    OT* __restrict__ C, int M, int N, int K) {
  __shared__ u16 As[128 * 64];
  __shared__ u16 Bs[128 * 64];
  int tid = threadIdx.x, lane = tid & 63, wid = tid >> 6;
  int nbn = N >> 7;
  int nwg = gridDim.x;
  int bid = blockIdx.x;
  int cpx = nwg >> 3;
  int swz = (bid & 7) * cpx + (bid >> 3);
  int bm = swz / nbn, bn = swz % nbn;
  int wr = wid >> 1, wc = wid & 1;

  f32x4 acc[4][4];
#pragma unroll
  for (int m = 0; m < 4; m++)
#pragma unroll
    for (int n = 0; n < 4; n++) acc[m][n] = (f32x4){0.f, 0.f, 0.f, 0.f};

  int row_in = lane >> 3;
  int col8 = lane & 7;
  const u16* Abase = A + ((size_t)(bm * 128 + wid * 32 + row_in)) * K + col8 * 8;
  const u16* Bbase = Bm + ((size_t)(bn * 128 + wid * 32 + row_in)) * K + col8 * 8;

  for (int kt = 0; kt < K; kt += 64) {
#pragma unroll
    for (int it = 0; it < 4; ++it) {
      gload_lds16(Abase + (size_t)(it * 8) * K + kt, &As[(wid * 32 + it * 8) * 64]);
      gload_lds16(Bbase + (size_t)(it * 8) * K + kt, &Bs[(wid * 32 + it * 8) * 64]);
    }
    __syncthreads();
#pragma unroll
    for (int kk = 0; kk < 2; ++kk) {
      int koff = kk * 32 + (lane >> 4) * 8;
      bf16x8 af[4], bfr[4];
      int rowa = wr * 64 + (lane & 15);
      int rowb = wc * 64 + (lane & 15);
#pragma unroll
      for (int m = 0; m < 4; m++) {
        ushort8v t8 = *reinterpret_cast<const ushort8v*>(&As[(rowa + m * 16) * 64 + koff]);
        af[m] = __builtin_bit_cast(bf16x8, t8);
      }
#pragma unroll
      for (int n = 0; n < 4; n++) {
        ushort8v t8 = *reinterpret_cast<const ushort8v*>(&Bs[(rowb + n * 16) * 64 + koff]);
        bfr[n] = __builtin_bit_cast(bf16x8, t8);
      }
#pragma unroll
      for (int m = 0; m < 4; m++)
#pragma unroll
        for (int n = 0; n < 4; n++)
          acc[m][n] = __builtin_amdgcn_mfma_f32_16x16x32_bf16(af[m], bfr[n], acc[m][n], 0, 0, 0);
    }
    __syncthreads();
  }

  int crow0 = bm * 128 + wr * 64 + (lane >> 4) * 4;
  int ccol = bn * 128 + wc * 64 + (lane & 15);
#pragma unroll
  for (int m = 0; m < 4; m++) {
#pragma unroll
    for (int q = 0; q < 4; q++) {
      OT* cp = C + (size_t)(crow0 + m * 16 + q) * N + ccol;
#pragma unroll
      for (int n = 0; n < 4; n++) {
        if constexpr (sizeof(OT) == 2)
          cp[n * 16] = (OT)f2bf(acc[m][n][q]);
        else
          cp[n * 16] = (OT)acc[m][n][q];
      }
    }
  }
}

// ---------------- scan phase 1 (MFMA): S_c[s,d] = sum_i w_s^{L-1-i} k_i[s] v_i[d] ----------------
template <int CHL>
__global__ __launch_bounds__(128) void scan_phase1_mfma(
    const u16* __restrict__ Kb, const u16* __restrict__ Vb,
    const float* __restrict__ td, float* __restrict__ chunks) {
  constexpr int NCH = T_ / CHL;
  constexpr int LDW = CHL + 8;
  __shared__ u16 Ash[2][64 * LDW];
  __shared__ u16 Vsh[2][64 * LDW];
  int lane = threadIdx.x & 63, wib = threadIdx.x >> 6;
  int gw = blockIdx.x * 2 + wib;
  int c = gw & (NCH - 1), bh = gw / NCH;
  int h = bh & 31, b = bh >> 5;

  size_t base = ((size_t)b * T_ + (size_t)c * CHL) * C_ + h * 64 + lane;
  const u16* Kp = Kb + base;
  const u16* Vp = Vb + base;

  {
    float w = __expf(-__expf(td[h * 64 + lane]));
    u16* Arow = &Ash[wib][lane * LDW];
    float p = 1.f;
#pragma unroll
    for (int i4 = CHL - 4; i4 >= 0; i4 -= 4) {
      float a3 = bf2f(Kp[(size_t)(i4 + 3) * C_]) * p; p *= w;
      float a2 = bf2f(Kp[(size_t)(i4 + 2) * C_]) * p; p *= w;
      float a1 = bf2f(Kp[(size_t)(i4 + 1) * C_]) * p; p *= w;
      float a0 = bf2f(Kp[(size_t)(i4 + 0) * C_]) * p; p *= w;
      ushort4 pk;
      pk.x = f2bf(a0); pk.y = f2bf(a1); pk.z = f2bf(a2); pk.w = f2bf(a3);
      *reinterpret_cast<ushort4*>(&Arow[i4]) = pk;
    }
  }
  {
    u16* Vrow = &Vsh[wib][lane * LDW];
#pragma unroll
    for (int i4 = 0; i4 < CHL; i4 += 4) {
      ushort4 pk;
      pk.x = Vp[(size_t)(i4 + 0) * C_];
      pk.y = Vp[(size_t)(i4 + 1) * C_];
      pk.z = Vp[(size_t)(i4 + 2) * C_];
      pk.w = Vp[(size_t)(i4 + 3) * C_];
      *reinterpret_cast<ushort4*>(&Vrow[i4]) = pk;
    }
  }

  f32x4 acc[4][4];
#pragma unroll
  for (int m = 0; m < 4; m++)
#pragma unroll
    for (int n = 0; n < 4; n++) acc[m][n] = (f32x4){0.f, 0.f, 0.f, 0.f};

#pragma unroll
  for (int kb = 0; kb < CHL / 32; kb++) {
    int ko = kb * 32 + (lane >> 4) * 8;
    bf16x8 Af[4], Bf[4];
#pragma unroll
    for (int m = 0; m < 4; m++) {
      ushort8v t8 = *reinterpret_cast<const ushort8v*>(&Ash[wib][(m * 16 + (lane & 15)) * LDW + ko]);
      Af[m] = __builtin_bit_cast(bf16x8, t8);
    }
#pragma unroll
    for (int n = 0; n < 4; n++) {
      ushort8v t8 = *reinterpret_cast<const ushort8v*>(&Vsh[wib][(n * 16 + (lane & 15)) * LDW + ko]);
      Bf[n] = __builtin_bit_cast(bf16x8, t8);
    }
#pragma unroll
    for (int m = 0; m < 4; m++)
#pragma unroll
      for (int n = 0; n < 4; n++)
        acc[m][n] = __builtin_amdgcn_mfma_f32_16x16x32_bf16(Af[m], Bf[n], acc[m][n], 0, 0, 0);
  }

  float* outp = chunks + (((size_t)c * B_ + b) * H_ + h) * 4096;
  int r0 = (lane >> 4) * 4, c0 = lane & 15;
#pragma unroll
  for (int m = 0; m < 4; m++)
#pragma unroll
    for (int n = 0; n < 4; n++)
#pragma unroll
      for (int q = 0; q < 4; q++)
        outp[(size_t)(m * 16 + r0 + q) * 64 + n * 16 + c0] = acc[m][n][q];
}

// ---------------- scan phase 1 (scalar fallback) ----------------
template <int NCH, int CHL>
__global__ __launch_bounds__(256) void scan_phase1(
    const u16* __restrict__ Kb, const u16* __restrict__ Vb,
    const float* __restrict__ td, float* __restrict__ chunks) {
  int lane = threadIdx.x & 63;
  int gw = (blockIdx.x * 256 + threadIdx.x) >> 6;
  int c = gw & (NCH - 1), bh = gw / NCH;
  int h = bh & 31, b = bh >> 5;
  const float* tdh = td + h * 64;
  float wreg[64];
#pragma unroll
  for (int s = 0; s < 64; s++) wreg[s] = __expf(-__expf(tdh[s]));
  float st[64];
#pragma unroll
  for (int s = 0; s < 64; s++) st[s] = 0.f;
  size_t base = ((size_t)b * T_ + (size_t)c * CHL) * C_ + h * 64 + lane;
  const u16* Kp = Kb + base;
  const u16* Vp = Vb + base;
  for (int t = 0; t < CHL; t++) {
    float kcur = bf2f(Kp[(size_t)t * C_]), vcur = bf2f(Vp[(size_t)t * C_]);
#pragma unroll
    for (int s = 0; s < 64; s++) {
      float ks = __shfl(kcur, s);
      st[s] = fmaf(wreg[s], st[s], ks * vcur);
    }
  }
  float* outp = chunks + (((size_t)c * B_ + b) * H_ + h) * 4096 + lane;
#pragma unroll
  for (int s = 0; s < 64; s++) outp[s * 64] = st[s];
}

// ---------------- scan phase 2 ----------------
template <int NCH, int CHL>
__global__ __launch_bounds__(256) void scan_phase2(
    const float* __restrict__ st0, const float* __restrict__ td,
    float* __restrict__ chunks, float* __restrict__ state_out) {
  int idx = blockIdx.x * 256 + threadIdx.x;
  int h = (idx >> 12) & 31;
  int s = (idx >> 6) & 63;
  float wL = __expf(-(float)CHL * __expf(td[h * 64 + s]));
  float st = st0[idx];
#pragma unroll
  for (int cc = 0; cc < NCH; cc++) {
    size_t off = (size_t)cc * 524288 + idx;
    float sc = chunks[off];
    chunks[off] = st;
    st = fmaf(wL, st, sc);
  }
  state_out[idx] = st;
}

// ---------------- scan phase 3 (MFMA, CHL=64, 16-step sub-blocks) ----------------
// One wave per (b,h,chunk). State St[s,d] fp32 in C-layout regs. Per sub-block:
//   O_cross = (r*w^i) @ St_bf16   (St transposed via small LDS)
//   A[i,j]  = sum_s (r w^{i-8})(k w^{7-j}) for j<i ; diag = sum_s r u k
//   O_intra = A @ V ;  St = w^16*St + K̄^T @ V
__global__ __launch_bounds__(256) void scan_phase3_mfma(
    const u16* __restrict__ Rb, const u16* __restrict__ Kb,
    const u16* __restrict__ Vb, const float* __restrict__ td,
    const float* __restrict__ tf, const float* __restrict__ chunks,
    const u16* __restrict__ Gb, const float* __restrict__ lnw,
    const float* __restrict__ lnb, u16* __restrict__ Y) {
  // per-wave LDS: Kt[16][64], Vt[16][64], StT[64][40], AT[16][40]
  __shared__ __align__(16) u16 smem[4][5248];
  int lane = threadIdx.x & 63, wib = threadIdx.x >> 6;
  int gw = blockIdx.x * 4 + wib;
  int c = gw & 31, bh = gw >> 5;
  int h = bh & 31, b = bh >> 5;
  int a = lane & 15, g = lane >> 4;
  int h0 = h * 64;

  u16* Kt = smem[wib];
  u16* Vt = Kt + 1024;
  u16* StT = Vt + 1024;      // [d][40] (s-half local, 32 used + pad)
  u16* AT = StT + 2560;      // [i][40] (j in [0,16) used, [16,40) zero)

  // ---- per-wave scale tables (all decay-bounded or |exp|<=8*ew) ----
  f32x8 sA[2], sB[2], sC[2], uA[2];
#pragma unroll
  for (int kk = 0; kk < 2; kk++) {
#pragma unroll
    for (int e = 0; e < 8; e++) {
      int s = kk * 32 + g * 8 + e;
      float ew = __expf(td[h0 + s]);
      sA[kk][e] = __expf(-(float)a * ew);            // w_s^i          (i = a)
      sB[kk][e] = __expf(-((float)a - 8.f) * ew);    // w_s^{i-8}
      sC[kk][e] = __expf(-(7.f - (float)a) * ew);    // w_s^{7-j}      (j = a)
      uA[kk][e] = tf[h0 + s];
    }
  }
  f32x4 sE[4];   // w_s^16 at acc rows s = ms*16 + g*4 + q
  f32x4 ewD;     // exp(td) at s = ms*16 + a (for K̄ scatter scale)
#pragma unroll
  for (int ms = 0; ms < 4; ms++) {
    ewD[ms] = __expf(td[h0 + ms * 16 + a]);
#pragma unroll
    for (int q = 0; q < 4; q++)
      sE[ms][q] = __expf(-16.f * __expf(td[h0 + ms * 16 + g * 4 + q]));
  }
  float lwv[4], lbv[4];
#pragma unroll
  for (int nd = 0; nd < 4; nd++) {
    lwv[nd] = lnw[h0 + nd * 16 + a];
    lbv[nd] = lnb[h0 + nd * 16 + a];
  }

  // ---- init state from chunk boundary ----
  f32x4 St[4][4];
  const float* cpc = chunks + (((size_t)c * B_ + b) * H_ + h) * 4096;
#pragma unroll
  for (int ms = 0; ms < 4; ms++)
#pragma unroll
    for (int nd = 0; nd < 4; nd++)
#pragma unroll
      for (int q = 0; q < 4; q++)
        St[ms][nd][q] = cpc[(size_t)(ms * 16 + g * 4 + q) * 64 + nd * 16 + a];

  // zero AT pad cols [16,40)
#pragma unroll
  for (int z = 0; z < 6; z++) {
    int idx = z * 64 + lane;          // 0..383
    int row = idx / 24, col = 16 + idx % 24;
    AT[row * 40 + col] = 0;
  }

  size_t tbase = ((size_t)b * T_ + (size_t)c * 64) * C_ + h0;

  for (int sb = 0; sb < 4; sb++) {
    size_t rb0 = tbase + (size_t)(sb * 16) * C_;

    // r,k fragments direct from global (row = a, cols kk*32 + g*8 .. +7)
    ushort8v r8[2], k8[2];
#pragma unroll
    for (int kk = 0; kk < 2; kk++) {
      r8[kk] = *reinterpret_cast<const ushort8v*>(Rb + rb0 + (size_t)a * C_ + kk * 32 + g * 8);
      k8[kk] = *reinterpret_cast<const ushort8v*>(Kb + rb0 + (size_t)a * C_ + kk * 32 + g * 8);
    }
    // stage K,V tiles [16][64] to LDS (coalesced)
    {
      int srow = lane >> 3;
      int scol = (lane & 7) * 8;
      *reinterpret_cast<ushort8v*>(&Kt[srow * 64 + scol]) =
          *reinterpret_cast<const ushort8v*>(Kb + rb0 + (size_t)srow * C_ + scol);
      *reinterpret_cast<ushort8v*>(&Kt[(srow + 8) * 64 + scol]) =
          *reinterpret_cast<const ushort8v*>(Kb + rb0 + (size_t)(srow + 8) * C_ + scol);
      *reinterpret_cast<ushort8v*>(&Vt[srow * 64 + scol]) =
          *reinterpret_cast<const ushort8v*>(Vb + rb0 + (size_t)srow * C_ + scol);
      *reinterpret_cast<ushort8v*>(&Vt[(srow + 8) * 64 + scol]) =
          *reinterpret_cast<const ushort8v*>(Vb + rb0 + (size_t)(srow + 8) * C_ + scol);
    }

    f32x4 O[4];
#pragma unroll
    for (int nd = 0; nd < 4; nd++) O[nd] = (f32x4){0.f, 0.f, 0.f, 0.f};

    // ---- O_cross: StT write (bf16) then R̃ @ St ----
#pragma unroll
    for (int kk = 0; kk < 2; kk++) {
#pragma unroll
      for (int msl = 0; msl < 2; msl++) {
        int ms = kk * 2 + msl;
#pragma unroll
        for (int nd = 0; nd < 4; nd++) {
          ushort4 pk;
          pk.x = f2bf(St[ms][nd][0]); pk.y = f2bf(St[ms][nd][1]);
          pk.z = f2bf(St[ms][nd][2]); pk.w = f2bf(St[ms][nd][3]);
          *reinterpret_cast<ushort4*>(&StT[(a + nd * 16) * 40 + msl * 16 + g * 4]) = pk;
        }
      }
      // r̃ frag
      ushort8v rt;
#pragma unroll
      for (int e = 0; e < 8; e++) rt[e] = f2bf(bf2f(r8[kk][e]) * sA[kk][e]);
      bf16x8 rtf = __builtin_bit_cast(bf16x8, rt);
#pragma unroll
      for (int nd = 0; nd < 4; nd++) {
        ushort8v sfr = *reinterpret_cast<const ushort8v*>(&StT[(a + nd * 16) * 40 + g * 8]);
        O[nd] = __builtin_amdgcn_mfma_f32_16x16x32_bf16(
            rtf, __builtin_bit_cast(bf16x8, sfr), O[nd], 0, 0, 0);
      }
    }

    // ---- diag term p_i = sum_s r u k ----
    float p = 0.f;
#pragma unroll
    for (int kk = 0; kk < 2; kk++)
#pragma unroll
      for (int e = 0; e < 8; e++)
        p = fmaf(bf2f(r8[kk][e]) * uA[kk][e], bf2f(k8[kk][e]), p);
    p += __shfl_xor(p, 16);
    p += __shfl_xor(p, 32);

    // ---- A matrix (transposed in C-layout): rows j, cols i ----
    f32x4 Am = (f32x4){0.f, 0.f, 0.f, 0.f};
#pragma unroll
    for (int kk = 0; kk < 2; kk++) {
      ushort8v kh, rh;
#pragma unroll
      for (int e = 0; e < 8; e++) {
        kh[e] = f2bf(bf2f(k8[kk][e]) * sC[kk][e]);
        rh[e] = f2bf(bf2f(r8[kk][e]) * sB[kk][e]);
      }
      Am = __builtin_amdgcn_mfma_f32_16x16x32_bf16(
          __builtin_bit_cast(bf16x8, kh), __builtin_bit_cast(bf16x8, rh), Am, 0, 0, 0);
    }
    // mask (keep j<i), diag=p, write A[i][j] to AT
    {
      ushort4 aw;
#pragma unroll
      for (int q = 0; q < 4; q++) {
        int jr = g * 4 + q;
        float v = (jr < a) ? Am[q] : ((jr == a) ? p : 0.f);
        ((u16*)&aw)[q] = f2bf(v);
      }
      *reinterpret_cast<ushort4*>(&AT[a * 40 + g * 4]) = aw;
    }
    bf16x8 afrag;
    {
      ushort8v t8 = *reinterpret_cast<const ushort8v*>(&AT[a * 40 + g * 8]);
      afrag = __builtin_bit_cast(bf16x8, t8);
    }

    // ---- V^T fragments (cols d, k-dim j; zeros for j>=16) ----
    bf16x8 vfrag[4];
#pragma unroll
    for (int nd = 0; nd < 4; nd++) {
      ushort8v t8;
      if (g < 2) {
#pragma unroll
        for (int e = 0; e < 8; e++) t8[e] = Vt[(g * 8 + e) * 64 + a + nd * 16];
      } else {
#pragma unroll
        for (int e = 0; e < 8; e++) t8[e] = 0;
      }
      vfrag[nd] = __builtin_bit_cast(bf16x8, t8);
    }

    // ---- O_intra = A @ V ----
#pragma unroll
    for (int nd = 0; nd < 4; nd++)
      O[nd] = __builtin_amdgcn_mfma_f32_16x16x32_bf16(afrag, vfrag[nd], O[nd], 0, 0, 0);

    // ---- St = w^16 * St + K̄^T @ V ----
#pragma unroll
    for (int ms = 0; ms < 4; ms++)
#pragma unroll
      for (int nd = 0; nd < 4; nd++)
#pragma unroll
        for (int q = 0; q < 4; q++) St[ms][nd][q] *= sE[ms][q];

#pragma unroll
    for (int ms = 0; ms < 4; ms++) {
      ushort8v kt8;
      if (g < 2) {
#pragma unroll
        for (int e = 0; e < 8; e++) {
          int j = g * 8 + e;
          float f = bf2f(Kt[j * 64 + ms * 16 + a]) * __expf(-(15.f - (float)j) * ewD[ms]);
          kt8[e] = f2bf(f);
        }
      } else {
#pragma unroll
        for (int e = 0; e < 8; e++) kt8[e] = 0;
      }
      bf16x8 kf = __builtin_bit_cast(bf16x8, kt8);
#pragma unroll
      for (int nd = 0; nd < 4; nd++)
        St[ms][nd] = __builtin_amdgcn_mfma_f32_16x16x32_bf16(kf, vfrag[nd], St[ms][nd], 0, 0, 0);
    }

    // ---- groupnorm (/8) * ln, * silu(gate), store bf16 ----
#pragma unroll
    for (int nd = 0; nd < 4; nd++)
#pragma unroll
      for (int q = 0; q < 4; q++) O[nd][q] *= 0.125f;
#pragma unroll
    for (int q = 0; q < 4; q++) {
      float ssum = O[0][q] + O[1][q] + O[2][q] + O[3][q];
      ssum += __shfl_xor(ssum, 1); ssum += __shfl_xor(ssum, 2);
      ssum += __shfl_xor(ssum, 4); ssum += __shfl_xor(ssum, 8);
      float mean = ssum * (1.f / 64.f);
      float vv = 0.f;
#pragma unroll
      for (int nd = 0; nd < 4; nd++) {
        float d = O[nd][q] - mean;
        vv = fmaf(d, d, vv);
      }
      vv += __shfl_xor(vv, 1); vv += __shfl_xor(vv, 2);
      vv += __shfl_xor(vv, 4); vv += __shfl_xor(vv, 8);
      float rs = rsqrtf(vv * (1.f / 64.f) + 1e-5f);
      size_t rowoff = rb0 + (size_t)(g * 4 + q) * C_;
#pragma unroll
      for (int nd = 0; nd < 4; nd++) {
        float xn = (O[nd][q] - mean) * rs;
        float gv = bf2f(Gb[rowoff + nd * 16 + a]);
        float sg = gv / (1.f + __expf(-gv));
        Y[rowoff + nd * 16 + a] = f2bf((xn * lwv[nd] + lbv[nd]) * sg);
      }
    }
  }
}

// ---------------- scan phase 3 (scalar fallback, NCH16) ----------------
template <int NCH, int CHL>
__global__ __launch_bounds__(256) void scan_phase3(
    const u16* __restrict__ Rb, const u16* __restrict__ Kb,
    const u16* __restrict__ Vb, const float* __restrict__ td,
    const float* __restrict__ tf, const float* __restrict__ chunks,
    const u16* __restrict__ Gb, const float* __restrict__ lnw,
    const float* __restrict__ lnb, u16* __restrict__ Y) {
  int lane = threadIdx.x & 63;
  int gw = (blockIdx.x * 256 + threadIdx.x) >> 6;
  int c = gw & (NCH - 1), bh = gw / NCH;
  int h = bh & 31, b = bh >> 5;
  const float* tdh = td + h * 64;
  float wreg[64];
#pragma unroll
  for (int s = 0; s < 64; s++) wreg[s] = __expf(-__expf(tdh[s]));
  float u_own = tf[h * 64 + lane];
  float lw = lnw[h * 64 + lane];
  float lb = lnb[h * 64 + lane];
  float st[64];
  const float* cp = chunks + (((size_t)c * B_ + b) * H_ + h) * 4096 + lane;
#pragma unroll
  for (int s = 0; s < 64; s++) st[s] = cp[s * 64];
  size_t base = ((size_t)b * T_ + (size_t)c * CHL) * C_ + h * 64 + lane;
  const u16* Rp = Rb + base;
  const u16* Kp = Kb + base;
  const u16* Vp = Vb + base;
  const u16* Gp = Gb + base;
  u16* Yp = Y + base;
  for (int t = 0; t < CHL; t++) {
    float rcur = bf2f(Rp[(size_t)t * C_]);
    float kcur = bf2f(Kp[(size_t)t * C_]);
    float vcur = bf2f(Vp[(size_t)t * C_]);
    float p = rcur * u_own * kcur;
#pragma unroll
    for (int off = 32; off >= 1; off >>= 1) p += __shfl_xor(p, off);
    float acc = 0.f;
#pragma unroll
    for (int s = 0; s < 64; s++) {
      float rs = __shfl(rcur, s);
      float ks = __shfl(kcur, s);
      acc = fmaf(rs, st[s], acc);
      st[s] = fmaf(wreg[s], st[s], ks * vcur);
    }
    float o = fmaf(p, vcur, acc);
    float x = o * 0.125f;
    float sum = x;
#pragma unroll
    for (int off = 32; off >= 1; off >>= 1) sum += __shfl_xor(sum, off);
    float mean = sum * (1.f / 64.f);
    float d = x - mean;
    float v2 = d * d;
#pragma unroll
    for (int off = 32; off >= 1; off >>= 1) v2 += __shfl_xor(v2, off);
    float var = v2 * (1.f / 64.f);
    float xn = d * rsqrtf(var + 1e-5f);
    float gg = bf2f(Gp[(size_t)t * C_]);
    float sg = gg / (1.f + __expf(-gg));
    Yp[(size_t)t * C_] = f2bf((xn * lw + lb) * sg);
  }
}

extern "C" void kernel_launch(void* const* d_in, const int* in_sizes, int n_in,
                              void* d_out, int out_size, void* d_ws, size_t ws_size,
                              hipStream_t stream) {
  const float* hidden = (const float*)d_in[0];
  const float* state0 = (const float*)d_in[1];
  const float* td = (const float*)d_in[2];
  const float* tf = (const float*)d_in[3];
  const float* mk = (const float*)d_in[4];
  const float* mv = (const float*)d_in[5];
  const float* mr = (const float*)d_in[6];
  const float* mg = (const float*)d_in[7];
  const float* kw = (const float*)d_in[8];
  const float* vw = (const float*)d_in[9];
  const float* rw = (const float*)d_in[10];
  const float* gw = (const float*)d_in[11];
  const float* ow = (const float*)d_in[12];
  const float* lnw = (const float*)d_in[13];
  const float* lnb = (const float*)d_in[14];

  float* out = (float*)d_out;
  float* state_f = out + (size_t)B_ * T_ * C_;

  char* ws = (char*)d_ws;
  u16* mixA = (u16*)ws;    ws += (size_t)B_ * T_ * C_ * 2;
  u16* wb = (u16*)ws;      ws += (size_t)C_ * C_ * 2;
  u16* rb = (u16*)ws;      ws += (size_t)B_ * T_ * C_ * 2;
  u16* kb = (u16*)ws;      ws += (size_t)B_ * T_ * C_ * 2;
  u16* vb = (u16*)ws;      ws += (size_t)B_ * T_ * C_ * 2;
  u16* gb = (u16*)ws;      ws += (size_t)B_ * T_ * C_ * 2;
  float* chunks = (float*)ws;
  size_t fixed = (size_t)(ws - (char*)d_ws);
  size_t chunks32 = (size_t)32 * B_ * H_ * S_ * S_ * 4;
  bool use32 = (ws_size >= fixed + chunks32);

  dim3 blk(256);
  int mixGrid = (B_ * T_ * C_ / 4) / 256;
  int convN4 = C_ * C_ / 4;
  int convGrid = convN4 / 256;
  int gemmGrid = (B_ * T_ / 128) * (C_ / 128);

  mix_cast_kernel<<<mixGrid, blk, 0, stream>>>(hidden, mr, mixA);
  conv_bf16_kernel<<<convGrid, blk, 0, stream>>>(rw, wb, convN4);
  gemm_bt<u16><<<gemmGrid, blk, 0, stream>>>(mixA, wb, rb, B_ * T_, C_, C_);
  mix_cast_kernel<<<mixGrid, blk, 0, stream>>>(hidden, mk, mixA);
  conv_bf16_kernel<<<convGrid, blk, 0, stream>>>(kw, wb, convN4);
  gemm_bt<u16><<<gemmGrid, blk, 0, stream>>>(mixA, wb, kb, B_ * T_, C_, C_);
  mix_cast_kernel<<<mixGrid, blk, 0, stream>>>(hidden, mv, mixA);
  conv_bf16_kernel<<<convGrid, blk, 0, stream>>>(vw, wb, convN4);
  gemm_bt<u16><<<gemmGrid, blk, 0, stream>>>(mixA, wb, vb, B_ * T_, C_, C_);
  mix_cast_kernel<<<mixGrid, blk, 0, stream>>>(hidden, mg, mixA);
  conv_bf16_kernel<<<convGrid, blk, 0, stream>>>(gw, wb, convN4);
  gemm_bt<u16><<<gemmGrid, blk, 0, stream>>>(mixA, wb, gb, B_ * T_, C_, C_);

  if (use32) {
    scan_phase1_mfma<64><<<(B_ * H_ * 32) / 2, dim3(128), 0, stream>>>(kb, vb, td, chunks);
    scan_phase2<32, 64><<<2048, blk, 0, stream>>>(state0, td, chunks, state_f);
    scan_phase3_mfma<<<(B_ * H_ * 32) / 4, blk, 0, stream>>>(rb, kb, vb, td, tf, chunks, gb, lnw, lnb, mixA);
  } else {
    scan_phase1<16, 128><<<(B_ * H_ * 16) / 4, blk, 0, stream>>>(kb, vb, td, chunks);
    scan_phase2<16, 128><<<2048, blk, 0, stream>>>(state0, td, chunks, state_f);
    scan_phase3<16, 128><<<(B_ * H_ * 16) / 4, blk, 0, stream>>>(rb, kb, vb, td, tf, chunks, gb, lnw, lnb, mixA);
  }

  conv_bf16_kernel<<<convGrid, blk, 0, stream>>>(ow, wb, convN4);
  gemm_bt<float><<<gemmGrid, blk, 0, stream>>>(mixA, wb, out, B_ * T_, C_, C_);
}

// Round 6
// 724.327 us; speedup vs baseline: 1.7174x; 1.0934x over previous
//
#include <hip/hip_runtime.h>
#include <hip/hip_bf16.h>

typedef unsigned short u16;
typedef __bf16 bf16x8 __attribute__((ext_vector_type(8)));
typedef unsigned short ushort8v __attribute__((ext_vector_type(8)));
typedef float f32x4 __attribute__((ext_vector_type(4)));
typedef float f32x8 __attribute__((ext_vector_type(8)));

#define B_ 4
#define T_ 2048
#define C_ 2048
#define H_ 32
#define S_ 64

__device__ __forceinline__ u16 f2bf(float x) {
  unsigned int u = __float_as_uint(x);
  unsigned int r = (u + 0x7fffu + ((u >> 16) & 1u)) >> 16;
  return (u16)r;
}
__device__ __forceinline__ float bf2f(u16 x) {
  return __uint_as_float(((unsigned int)x) << 16);
}
__device__ __forceinline__ void gload_lds16(const void* g, void* l) {
  __builtin_amdgcn_global_load_lds(
      (const __attribute__((address_space(1))) void*)g,
      (__attribute__((address_space(3))) void*)l, 16, 0, 0);
}

#define VM10 asm volatile("s_waitcnt vmcnt(10)" ::: "memory")
#define VM8 asm volatile("s_waitcnt vmcnt(8)" ::: "memory")
#define VM4 asm volatile("s_waitcnt vmcnt(4)" ::: "memory")
#define VM0 asm volatile("s_waitcnt vmcnt(0)" ::: "memory")
#define BARR __builtin_amdgcn_s_barrier()
#define SCB __builtin_amdgcn_sched_barrier(0)

// ---------------- mix + cast to bf16 ----------------
__global__ __launch_bounds__(256) void mix_cast_kernel(
    const float* __restrict__ hidden, const float* __restrict__ mixp,
    u16* __restrict__ out) {
  int idx = blockIdx.x * 256 + threadIdx.x;
  int c4 = idx & 511;
  int bt = idx >> 9;
  int t = bt & (T_ - 1);
  float4 h = reinterpret_cast<const float4*>(hidden)[idx];
  float4 m = reinterpret_cast<const float4*>(mixp)[c4];
  float4 sh = make_float4(0.f, 0.f, 0.f, 0.f);
  if (t != 0) sh = reinterpret_cast<const float4*>(hidden)[idx - 512];
  ushort4 o;
  o.x = f2bf(h.x * m.x + sh.x * (1.f - m.x));
  o.y = f2bf(h.y * m.y + sh.y * (1.f - m.y));
  o.z = f2bf(h.z * m.z + sh.z * (1.f - m.z));
  o.w = f2bf(h.w * m.w + sh.w * (1.f - m.w));
  reinterpret_cast<ushort4*>(out)[idx] = o;
}

// ---------------- fp32 -> bf16 weight cast ----------------
__global__ __launch_bounds__(256) void conv_bf16_kernel(
    const float* __restrict__ in, u16* __restrict__ out, int n4) {
  int i = blockIdx.x * 256 + threadIdx.x;
  if (i >= n4) return;
  float4 v = reinterpret_cast<const float4*>(in)[i];
  ushort4 o;
  o.x = f2bf(v.x); o.y = f2bf(v.y); o.z = f2bf(v.z); o.w = f2bf(v.w);
  reinterpret_cast<ushort4*>(out)[i] = o;
}

// ---------------- 256x256 8-phase bf16 GEMM: C[M,N] = A[M,K] * B[N,K]^T ----------------
// 512 threads = 8 waves (2 M x 4 N). BK=64 staged as 4 K-half tiles [256][32].
// LDS slots: [par*2 + khalf], 2-tile rotation; counted vmcnt(10) pipeline
// (needed half always exactly 6 phases old; ledger-verified incl. tails).
// T2 swizzle: chunk ^= (row>>1)&3 applied to global source + LDS read (both sides).
template <typename OT>
__global__ __launch_bounds__(512, 2) void gemm_bt256(
    const u16* __restrict__ A, const u16* __restrict__ Bm,
    OT* __restrict__ C, int M, int N, int K) {
  __shared__ u16 Asl[4][8192];
  __shared__ u16 Bsl[4][8192];
  const int tid = threadIdx.x, lane = tid & 63, w = tid >> 6;
  const int wr = w >> 2, wc = w & 3;
  const int nbn = N >> 8;
  const int nwg = gridDim.x, bid = blockIdx.x, cpx = nwg >> 3;
  const int swz = (bid & 7) * cpx + (bid >> 3);
  const int bm = swz / nbn, bn = swz % nbn;
  const int Ar0 = bm * 256, Br0 = bn * 256;

  // staging geometry: lane l covers row w*32 + (l>>2) (+16 for inst 1), chunk l&3.
  // source chunk pre-swizzled so linear LDS + swizzled read match (rule #21).
  const int rowoff = w * 32 + (lane >> 2);
  const int colswz = ((lane & 3) ^ ((lane >> 3) & 3)) * 8;
  const u16* Agl = A + (size_t)(Ar0 + rowoff) * K + colswz;
  const u16* Bgl = Bm + (size_t)(Br0 + rowoff) * K + colswz;
  const int lb = w * 1024;  // elems; inst1 at +512

  // read geometry: chunk = (lane>>4) ^ ((row>>1)&3); row bits 1-2 == lane bits 1-2.
  const int rdc = (((lane >> 4) ^ ((lane >> 1) & 3))) * 8;
  const int arow = wr * 128 + (lane & 15);
  const int brow = wc * 64 + (lane & 15);

  f32x4 acc[8][4];
#pragma unroll
  for (int m = 0; m < 8; m++)
#pragma unroll
    for (int n = 0; n < 4; n++) acc[m][n] = (f32x4){0.f, 0.f, 0.f, 0.f};

  auto STA = [&](int ktile, int kk, int slot) {
    const u16* g = Agl + ktile * 64 + kk * 32;
    gload_lds16(g, &Asl[slot][lb]);
    gload_lds16(g + (size_t)16 * K, &Asl[slot][lb + 512]);
  };
  auto STB = [&](int ktile, int kk, int slot) {
    const u16* g = Bgl + ktile * 64 + kk * 32;
    gload_lds16(g, &Bsl[slot][lb]);
    gload_lds16(g + (size_t)16 * K, &Bsl[slot][lb + 512]);
  };
  auto PH = [&](int P, int kk, int mh) {
    const u16* As_ = Asl[P * 2 + kk];
    const u16* Bs_ = Bsl[P * 2 + kk];
    bf16x8 af[4], bv[4];
    int ab = (arow + mh * 64) * 32 + rdc;
#pragma unroll
    for (int mf = 0; mf < 4; mf++)
      af[mf] = __builtin_bit_cast(bf16x8, *reinterpret_cast<const ushort8v*>(&As_[ab + mf * 512]));
    int bb = brow * 32 + rdc;
#pragma unroll
    for (int nf = 0; nf < 4; nf++)
      bv[nf] = __builtin_bit_cast(bf16x8, *reinterpret_cast<const ushort8v*>(&Bs_[bb + nf * 512]));
    __builtin_amdgcn_s_setprio(1);
#pragma unroll
    for (int mf = 0; mf < 4; mf++)
#pragma unroll
      for (int nf = 0; nf < 4; nf++)
        acc[mh * 4 + mf][nf] =
            __builtin_amdgcn_mfma_f32_16x16x32_bf16(af[mf], bv[nf], acc[mh * 4 + mf][nf], 0, 0, 0);
    __builtin_amdgcn_s_setprio(0);
  };

  const int NT = K >> 6;
  // prologue: halves 1..6 = t0.k0A, t0.k0B, t0.k1A, t0.k1B, t1.k0A, t1.k0B
  STA(0, 0, 0); STB(0, 0, 0);
  STA(0, 1, 1); STB(0, 1, 1);
  STA(1, 0, 2); STB(1, 0, 2);

  for (int T = 0; T + 2 < NT; ++T) {
    int P = T & 1, Q = P ^ 1;
    STA(T + 1, 1, Q * 2 + 1); VM10; BARR; SCB; PH(P, 0, 0); BARR;
    STB(T + 1, 1, Q * 2 + 1); VM10; BARR; SCB; PH(P, 0, 1); BARR;
    STA(T + 2, 0, P * 2 + 0); VM10; BARR; SCB; PH(P, 1, 0); BARR;
    STB(T + 2, 0, P * 2 + 0); VM10; BARR; SCB; PH(P, 1, 1); BARR;
  }
  {
    int T = NT - 2, P = T & 1, Q = P ^ 1;
    STA(T + 1, 1, Q * 2 + 1); VM10; BARR; SCB; PH(P, 0, 0); BARR;
    STB(T + 1, 1, Q * 2 + 1); VM10; BARR; SCB; PH(P, 0, 1); BARR;
    VM8; BARR; SCB; PH(P, 1, 0); BARR;
    VM8; BARR; SCB; PH(P, 1, 1); BARR;
  }
  {
    int P = (NT - 1) & 1;
    VM4; BARR; SCB; PH(P, 0, 0); BARR;
    VM4; BARR; SCB; PH(P, 0, 1); BARR;
    VM0; BARR; SCB; PH(P, 1, 0); BARR;
    VM0; BARR; SCB; PH(P, 1, 1);
  }

  int crow0 = Ar0 + wr * 128 + (lane >> 4) * 4;
  int ccol0 = Br0 + wc * 64 + (lane & 15);
#pragma unroll
  for (int mfg = 0; mfg < 8; mfg++) {
#pragma unroll
    for (int q = 0; q < 4; q++) {
      OT* cp = C + (size_t)(crow0 + mfg * 16 + q) * N + ccol0;
#pragma unroll
      for (int nf = 0; nf < 4; nf++) {
        if constexpr (sizeof(OT) == 2)
          cp[nf * 16] = (OT)f2bf(acc[mfg][nf][q]);
        else
          cp[nf * 16] = (OT)acc[mfg][nf][q];
      }
    }
  }
}

// ---------------- scan phase 1 (MFMA): S_c[s,d] = sum_i w_s^{L-1-i} k_i[s] v_i[d] ----------------
template <int CHL>
__global__ __launch_bounds__(128) void scan_phase1_mfma(
    const u16* __restrict__ Kb, const u16* __restrict__ Vb,
    const float* __restrict__ td, float* __restrict__ chunks) {
  constexpr int NCH = T_ / CHL;
  constexpr int LDW = CHL + 8;
  __shared__ u16 Ash[2][64 * LDW];
  __shared__ u16 Vsh[2][64 * LDW];
  int lane = threadIdx.x & 63, wib = threadIdx.x >> 6;
  int gw = blockIdx.x * 2 + wib;
  int c = gw & (NCH - 1), bh = gw / NCH;
  int h = bh & 31, b = bh >> 5;

  size_t base = ((size_t)b * T_ + (size_t)c * CHL) * C_ + h * 64 + lane;
  const u16* Kp = Kb + base;
  const u16* Vp = Vb + base;

  {
    float w = __expf(-__expf(td[h * 64 + lane]));
    u16* Arow = &Ash[wib][lane * LDW];
    float p = 1.f;
#pragma unroll
    for (int i4 = CHL - 4; i4 >= 0; i4 -= 4) {
      float a3 = bf2f(Kp[(size_t)(i4 + 3) * C_]) * p; p *= w;
      float a2 = bf2f(Kp[(size_t)(i4 + 2) * C_]) * p; p *= w;
      float a1 = bf2f(Kp[(size_t)(i4 + 1) * C_]) * p; p *= w;
      float a0 = bf2f(Kp[(size_t)(i4 + 0) * C_]) * p; p *= w;
      ushort4 pk;
      pk.x = f2bf(a0); pk.y = f2bf(a1); pk.z = f2bf(a2); pk.w = f2bf(a3);
      *reinterpret_cast<ushort4*>(&Arow[i4]) = pk;
    }
  }
  {
    u16* Vrow = &Vsh[wib][lane * LDW];
#pragma unroll
    for (int i4 = 0; i4 < CHL; i4 += 4) {
      ushort4 pk;
      pk.x = Vp[(size_t)(i4 + 0) * C_];
      pk.y = Vp[(size_t)(i4 + 1) * C_];
      pk.z = Vp[(size_t)(i4 + 2) * C_];
      pk.w = Vp[(size_t)(i4 + 3) * C_];
      *reinterpret_cast<ushort4*>(&Vrow[i4]) = pk;
    }
  }

  f32x4 acc[4][4];
#pragma unroll
  for (int m = 0; m < 4; m++)
#pragma unroll
    for (int n = 0; n < 4; n++) acc[m][n] = (f32x4){0.f, 0.f, 0.f, 0.f};

#pragma unroll
  for (int kb = 0; kb < CHL / 32; kb++) {
    int ko = kb * 32 + (lane >> 4) * 8;
    bf16x8 Af[4], Bf[4];
#pragma unroll
    for (int m = 0; m < 4; m++) {
      ushort8v t8 = *reinterpret_cast<const ushort8v*>(&Ash[wib][(m * 16 + (lane & 15)) * LDW + ko]);
      Af[m] = __builtin_bit_cast(bf16x8, t8);
    }
#pragma unroll
    for (int n = 0; n < 4; n++) {
      ushort8v t8 = *reinterpret_cast<const ushort8v*>(&Vsh[wib][(n * 16 + (lane & 15)) * LDW + ko]);
      Bf[n] = __builtin_bit_cast(bf16x8, t8);
    }
#pragma unroll
    for (int m = 0; m < 4; m++)
#pragma unroll
      for (int n = 0; n < 4; n++)
        acc[m][n] = __builtin_amdgcn_mfma_f32_16x16x32_bf16(Af[m], Bf[n], acc[m][n], 0, 0, 0);
  }

  float* outp = chunks + (((size_t)c * B_ + b) * H_ + h) * 4096;
  int r0 = (lane >> 4) * 4, c0 = lane & 15;
#pragma unroll
  for (int m = 0; m < 4; m++)
#pragma unroll
    for (int n = 0; n < 4; n++)
#pragma unroll
      for (int q = 0; q < 4; q++)
        outp[(size_t)(m * 16 + r0 + q) * 64 + n * 16 + c0] = acc[m][n][q];
}

// ---------------- scan phase 1 (scalar fallback) ----------------
template <int NCH, int CHL>
__global__ __launch_bounds__(256) void scan_phase1(
    const u16* __restrict__ Kb, const u16* __restrict__ Vb,
    const float* __restrict__ td, float* __restrict__ chunks) {
  int lane = threadIdx.x & 63;
  int gw = (blockIdx.x * 256 + threadIdx.x) >> 6;
  int c = gw & (NCH - 1), bh = gw / NCH;
  int h = bh & 31, b = bh >> 5;
  const float* tdh = td + h * 64;
  float wreg[64];
#pragma unroll
  for (int s = 0; s < 64; s++) wreg[s] = __expf(-__expf(tdh[s]));
  float st[64];
#pragma unroll
  for (int s = 0; s < 64; s++) st[s] = 0.f;
  size_t base = ((size_t)b * T_ + (size_t)c * CHL) * C_ + h * 64 + lane;
  const u16* Kp = Kb + base;
  const u16* Vp = Vb + base;
  for (int t = 0; t < CHL; t++) {
    float kcur = bf2f(Kp[(size_t)t * C_]), vcur = bf2f(Vp[(size_t)t * C_]);
#pragma unroll
    for (int s = 0; s < 64; s++) {
      float ks = __shfl(kcur, s);
      st[s] = fmaf(wreg[s], st[s], ks * vcur);
    }
  }
  float* outp = chunks + (((size_t)c * B_ + b) * H_ + h) * 4096 + lane;
#pragma unroll
  for (int s = 0; s < 64; s++) outp[s * 64] = st[s];
}

// ---------------- scan phase 2 ----------------
template <int NCH, int CHL>
__global__ __launch_bounds__(256) void scan_phase2(
    const float* __restrict__ st0, const float* __restrict__ td,
    float* __restrict__ chunks, float* __restrict__ state_out) {
  int idx = blockIdx.x * 256 + threadIdx.x;
  int h = (idx >> 12) & 31;
  int s = (idx >> 6) & 63;
  float wL = __expf(-(float)CHL * __expf(td[h * 64 + s]));
  float st = st0[idx];
#pragma unroll
  for (int cc = 0; cc < NCH; cc++) {
    size_t off = (size_t)cc * 524288 + idx;
    float sc = chunks[off];
    chunks[off] = st;
    st = fmaf(wL, st, sc);
  }
  state_out[idx] = st;
}

// ---------------- scan phase 3 (MFMA, CHL=64, 16-step sub-blocks) ----------------
__global__ __launch_bounds__(256) void scan_phase3_mfma(
    const u16* __restrict__ Rb, const u16* __restrict__ Kb,
    const u16* __restrict__ Vb, const float* __restrict__ td,
    const float* __restrict__ tf, const float* __restrict__ chunks,
    const u16* __restrict__ Gb, const float* __restrict__ lnw,
    const float* __restrict__ lnb, u16* __restrict__ Y) {
  __shared__ __align__(16) u16 smem[4][5248];
  int lane = threadIdx.x & 63, wib = threadIdx.x >> 6;
  int gw = blockIdx.x * 4 + wib;
  int c = gw & 31, bh = gw >> 5;
  int h = bh & 31, b = bh >> 5;
  int a = lane & 15, g = lane >> 4;
  int h0 = h * 64;

  u16* Kt = smem[wib];
  u16* Vt = Kt + 1024;
  u16* StT = Vt + 1024;
  u16* AT = StT + 2560;

  f32x8 sA[2], sB[2], sC[2], uA[2];
#pragma unroll
  for (int kk = 0; kk < 2; kk++) {
#pragma unroll
    for (int e = 0; e < 8; e++) {
      int s = kk * 32 + g * 8 + e;
      float ew = __expf(td[h0 + s]);
      sA[kk][e] = __expf(-(float)a * ew);
      sB[kk][e] = __expf(-((float)a - 8.f) * ew);
      sC[kk][e] = __expf(-(7.f - (float)a) * ew);
      uA[kk][e] = tf[h0 + s];
    }
  }
  f32x4 sE[4];
  f32x4 ewD;
#pragma unroll
  for (int ms = 0; ms < 4; ms++) {
    ewD[ms] = __expf(td[h0 + ms * 16 + a]);
#pragma unroll
    for (int q = 0; q < 4; q++)
      sE[ms][q] = __expf(-16.f * __expf(td[h0 + ms * 16 + g * 4 + q]));
  }
  float lwv[4], lbv[4];
#pragma unroll
  for (int nd = 0; nd < 4; nd++) {
    lwv[nd] = lnw[h0 + nd * 16 + a];
    lbv[nd] = lnb[h0 + nd * 16 + a];
  }

  f32x4 St[4][4];
  const float* cpc = chunks + (((size_t)c * B_ + b) * H_ + h) * 4096;
#pragma unroll
  for (int ms = 0; ms < 4; ms++)
#pragma unroll
    for (int nd = 0; nd < 4; nd++)
#pragma unroll
      for (int q = 0; q < 4; q++)
        St[ms][nd][q] = cpc[(size_t)(ms * 16 + g * 4 + q) * 64 + nd * 16 + a];

#pragma unroll
  for (int z = 0; z < 6; z++) {
    int idx = z * 64 + lane;
    int row = idx / 24, col = 16 + idx % 24;
    AT[row * 40 + col] = 0;
  }

  size_t tbase = ((size_t)b * T_ + (size_t)c * 64) * C_ + h0;

  for (int sb = 0; sb < 4; sb++) {
    size_t rb0 = tbase + (size_t)(sb * 16) * C_;

    ushort8v r8[2], k8[2];
#pragma unroll
    for (int kk = 0; kk < 2; kk++) {
      r8[kk] = *reinterpret_cast<const ushort8v*>(Rb + rb0 + (size_t)a * C_ + kk * 32 + g * 8);
      k8[kk] = *reinterpret_cast<const ushort8v*>(Kb + rb0 + (size_t)a * C_ + kk * 32 + g * 8);
    }
    {
      int srow = lane >> 3;
      int scol = (lane & 7) * 8;
      *reinterpret_cast<ushort8v*>(&Kt[srow * 64 + scol]) =
          *reinterpret_cast<const ushort8v*>(Kb + rb0 + (size_t)srow * C_ + scol);
      *reinterpret_cast<ushort8v*>(&Kt[(srow + 8) * 64 + scol]) =
          *reinterpret_cast<const ushort8v*>(Kb + rb0 + (size_t)(srow + 8) * C_ + scol);
      *reinterpret_cast<ushort8v*>(&Vt[srow * 64 + scol]) =
          *reinterpret_cast<const ushort8v*>(Vb + rb0 + (size_t)srow * C_ + scol);
      *reinterpret_cast<ushort8v*>(&Vt[(srow + 8) * 64 + scol]) =
          *reinterpret_cast<const ushort8v*>(Vb + rb0 + (size_t)(srow + 8) * C_ + scol);
    }

    f32x4 O[4];
#pragma unroll
    for (int nd = 0; nd < 4; nd++) O[nd] = (f32x4){0.f, 0.f, 0.f, 0.f};

#pragma unroll
    for (int kk = 0; kk < 2; kk++) {
#pragma unroll
      for (int msl = 0; msl < 2; msl++) {
        int ms = kk * 2 + msl;
#pragma unroll
        for (int nd = 0; nd < 4; nd++) {
          ushort4 pk;
          pk.x = f2bf(St[ms][nd][0]); pk.y = f2bf(St[ms][nd][1]);
          pk.z = f2bf(St[ms][nd][2]); pk.w = f2bf(St[ms][nd][3]);
          *reinterpret_cast<ushort4*>(&StT[(a + nd * 16) * 40 + msl * 16 + g * 4]) = pk;
        }
      }
      ushort8v rt;
#pragma unroll
      for (int e = 0; e < 8; e++) rt[e] = f2bf(bf2f(r8[kk][e]) * sA[kk][e]);
      bf16x8 rtf = __builtin_bit_cast(bf16x8, rt);
#pragma unroll
      for (int nd = 0; nd < 4; nd++) {
        ushort8v sfr = *reinterpret_cast<const ushort8v*>(&StT[(a + nd * 16) * 40 + g * 8]);
        O[nd] = __builtin_amdgcn_mfma_f32_16x16x32_bf16(
            rtf, __builtin_bit_cast(bf16x8, sfr), O[nd], 0, 0, 0);
      }
    }

    float p = 0.f;
#pragma unroll
    for (int kk = 0; kk < 2; kk++)
#pragma unroll
      for (int e = 0; e < 8; e++)
        p = fmaf(bf2f(r8[kk][e]) * uA[kk][e], bf2f(k8[kk][e]), p);
    p += __shfl_xor(p, 16);
    p += __shfl_xor(p, 32);

    f32x4 Am = (f32x4){0.f, 0.f, 0.f, 0.f};
#pragma unroll
    for (int kk = 0; kk < 2; kk++) {
      ushort8v kh, rh;
#pragma unroll
      for (int e = 0; e < 8; e++) {
        kh[e] = f2bf(bf2f(k8[kk][e]) * sC[kk][e]);
        rh[e] = f2bf(bf2f(r8[kk][e]) * sB[kk][e]);
      }
      Am = __builtin_amdgcn_mfma_f32_16x16x32_bf16(
          __builtin_bit_cast(bf16x8, kh), __builtin_bit_cast(bf16x8, rh), Am, 0, 0, 0);
    }
    {
      ushort4 aw;
#pragma unroll
      for (int q = 0; q < 4; q++) {
        int jr = g * 4 + q;
        float v = (jr < a) ? Am[q] : ((jr == a) ? p : 0.f);
        ((u16*)&aw)[q] = f2bf(v);
      }
      *reinterpret_cast<ushort4*>(&AT[a * 40 + g * 4]) = aw;
    }
    bf16x8 afrag;
    {
      ushort8v t8 = *reinterpret_cast<const ushort8v*>(&AT[a * 40 + g * 8]);
      afrag = __builtin_bit_cast(bf16x8, t8);
    }

    bf16x8 vfrag[4];
#pragma unroll
    for (int nd = 0; nd < 4; nd++) {
      ushort8v t8;
      if (g < 2) {
#pragma unroll
        for (int e = 0; e < 8; e++) t8[e] = Vt[(g * 8 + e) * 64 + a + nd * 16];
      } else {
#pragma unroll
        for (int e = 0; e < 8; e++) t8[e] = 0;
      }
      vfrag[nd] = __builtin_bit_cast(bf16x8, t8);
    }

#pragma unroll
    for (int nd = 0; nd < 4; nd++)
      O[nd] = __builtin_amdgcn_mfma_f32_16x16x32_bf16(afrag, vfrag[nd], O[nd], 0, 0, 0);

#pragma unroll
    for (int ms = 0; ms < 4; ms++)
#pragma unroll
      for (int nd = 0; nd < 4; nd++)
#pragma unroll
        for (int q = 0; q < 4; q++) St[ms][nd][q] *= sE[ms][q];

#pragma unroll
    for (int ms = 0; ms < 4; ms++) {
      ushort8v kt8;
      if (g < 2) {
#pragma unroll
        for (int e = 0; e < 8; e++) {
          int j = g * 8 + e;
          float f = bf2f(Kt[j * 64 + ms * 16 + a]) * __expf(-(15.f - (float)j) * ewD[ms]);
          kt8[e] = f2bf(f);
        }
      } else {
#pragma unroll
        for (int e = 0; e < 8; e++) kt8[e] = 0;
      }
      bf16x8 kf = __builtin_bit_cast(bf16x8, kt8);
#pragma unroll
      for (int nd = 0; nd < 4; nd++)
        St[ms][nd] = __builtin_amdgcn_mfma_f32_16x16x32_bf16(kf, vfrag[nd], St[ms][nd], 0, 0, 0);
    }

#pragma unroll
    for (int nd = 0; nd < 4; nd++)
#pragma unroll
      for (int q = 0; q < 4; q++) O[nd][q] *= 0.125f;
#pragma unroll
    for (int q = 0; q < 4; q++) {
      float ssum = O[0][q] + O[1][q] + O[2][q] + O[3][q];
      ssum += __shfl_xor(ssum, 1); ssum += __shfl_xor(ssum, 2);
      ssum += __shfl_xor(ssum, 4); ssum += __shfl_xor(ssum, 8);
      float mean = ssum * (1.f / 64.f);
      float vv = 0.f;
#pragma unroll
      for (int nd = 0; nd < 4; nd++) {
        float d = O[nd][q] - mean;
        vv = fmaf(d, d, vv);
      }
      vv += __shfl_xor(vv, 1); vv += __shfl_xor(vv, 2);
      vv += __shfl_xor(vv, 4); vv += __shfl_xor(vv, 8);
      float rs = rsqrtf(vv * (1.f / 64.f) + 1e-5f);
      size_t rowoff = rb0 + (size_t)(g * 4 + q) * C_;
#pragma unroll
      for (int nd = 0; nd < 4; nd++) {
        float xn = (O[nd][q] - mean) * rs;
        float gv = bf2f(Gb[rowoff + nd * 16 + a]);
        float sg = gv / (1.f + __expf(-gv));
        Y[rowoff + nd * 16 + a] = f2bf((xn * lwv[nd] + lbv[nd]) * sg);
      }
    }
  }
}

// ---------------- scan phase 3 (scalar fallback, NCH16) ----------------
template <int NCH, int CHL>
__global__ __launch_bounds__(256) void scan_phase3(
    const u16* __restrict__ Rb, const u16* __restrict__ Kb,
    const u16* __restrict__ Vb, const float* __restrict__ td,
    const float* __restrict__ tf, const float* __restrict__ chunks,
    const u16* __restrict__ Gb, const float* __restrict__ lnw,
    const float* __restrict__ lnb, u16* __restrict__ Y) {
  int lane = threadIdx.x & 63;
  int gw = (blockIdx.x * 256 + threadIdx.x) >> 6;
  int c = gw & (NCH - 1), bh = gw / NCH;
  int h = bh & 31, b = bh >> 5;
  const float* tdh = td + h * 64;
  float wreg[64];
#pragma unroll
  for (int s = 0; s < 64; s++) wreg[s] = __expf(-__expf(tdh[s]));
  float u_own = tf[h * 64 + lane];
  float lw = lnw[h * 64 + lane];
  float lb = lnb[h * 64 + lane];
  float st[64];
  const float* cp = chunks + (((size_t)c * B_ + b) * H_ + h) * 4096 + lane;
#pragma unroll
  for (int s = 0; s < 64; s++) st[s] = cp[s * 64];
  size_t base = ((size_t)b * T_ + (size_t)c * CHL) * C_ + h * 64 + lane;
  const u16* Rp = Rb + base;
  const u16* Kp = Kb + base;
  const u16* Vp = Vb + base;
  const u16* Gp = Gb + base;
  u16* Yp = Y + base;
  for (int t = 0; t < CHL; t++) {
    float rcur = bf2f(Rp[(size_t)t * C_]);
    float kcur = bf2f(Kp[(size_t)t * C_]);
    float vcur = bf2f(Vp[(size_t)t * C_]);
    float p = rcur * u_own * kcur;
#pragma unroll
    for (int off = 32; off >= 1; off >>= 1) p += __shfl_xor(p, off);
    float acc = 0.f;
#pragma unroll
    for (int s = 0; s < 64; s++) {
      float rs = __shfl(rcur, s);
      float ks = __shfl(kcur, s);
      acc = fmaf(rs, st[s], acc);
      st[s] = fmaf(wreg[s], st[s], ks * vcur);
    }
    float o = fmaf(p, vcur, acc);
    float x = o * 0.125f;
    float sum = x;
#pragma unroll
    for (int off = 32; off >= 1; off >>= 1) sum += __shfl_xor(sum, off);
    float mean = sum * (1.f / 64.f);
    float d = x - mean;
    float v2 = d * d;
#pragma unroll
    for (int off = 32; off >= 1; off >>= 1) v2 += __shfl_xor(v2, off);
    float var = v2 * (1.f / 64.f);
    float xn = d * rsqrtf(var + 1e-5f);
    float gg = bf2f(Gp[(size_t)t * C_]);
    float sg = gg / (1.f + __expf(-gg));
    Yp[(size_t)t * C_] = f2bf((xn * lw + lb) * sg);
  }
}

extern "C" void kernel_launch(void* const* d_in, const int* in_sizes, int n_in,
                              void* d_out, int out_size, void* d_ws, size_t ws_size,
                              hipStream_t stream) {
  const float* hidden = (const float*)d_in[0];
  const float* state0 = (const float*)d_in[1];
  const float* td = (const float*)d_in[2];
  const float* tf = (const float*)d_in[3];
  const float* mk = (const float*)d_in[4];
  const float* mv = (const float*)d_in[5];
  const float* mr = (const float*)d_in[6];
  const float* mg = (const float*)d_in[7];
  const float* kw = (const float*)d_in[8];
  const float* vw = (const float*)d_in[9];
  const float* rw = (const float*)d_in[10];
  const float* gw = (const float*)d_in[11];
  const float* ow = (const float*)d_in[12];
  const float* lnw = (const float*)d_in[13];
  const float* lnb = (const float*)d_in[14];

  float* out = (float*)d_out;
  float* state_f = out + (size_t)B_ * T_ * C_;

  char* ws = (char*)d_ws;
  u16* mixA = (u16*)ws;    ws += (size_t)B_ * T_ * C_ * 2;
  u16* wb = (u16*)ws;      ws += (size_t)C_ * C_ * 2;
  u16* rb = (u16*)ws;      ws += (size_t)B_ * T_ * C_ * 2;
  u16* kb = (u16*)ws;      ws += (size_t)B_ * T_ * C_ * 2;
  u16* vb = (u16*)ws;      ws += (size_t)B_ * T_ * C_ * 2;
  u16* gb = (u16*)ws;      ws += (size_t)B_ * T_ * C_ * 2;
  float* chunks = (float*)ws;
  size_t fixed = (size_t)(ws - (char*)d_ws);
  size_t chunks32 = (size_t)32 * B_ * H_ * S_ * S_ * 4;
  bool use32 = (ws_size >= fixed + chunks32);

  dim3 blk(256);
  int mixGrid = (B_ * T_ * C_ / 4) / 256;
  int convN4 = C_ * C_ / 4;
  int convGrid = convN4 / 256;
  int gemmGrid = (B_ * T_ / 256) * (C_ / 256);  // 256 blocks of 512 threads
  dim3 gblk(512);

  mix_cast_kernel<<<mixGrid, blk, 0, stream>>>(hidden, mr, mixA);
  conv_bf16_kernel<<<convGrid, blk, 0, stream>>>(rw, wb, convN4);
  gemm_bt256<u16><<<gemmGrid, gblk, 0, stream>>>(mixA, wb, rb, B_ * T_, C_, C_);
  mix_cast_kernel<<<mixGrid, blk, 0, stream>>>(hidden, mk, mixA);
  conv_bf16_kernel<<<convGrid, blk, 0, stream>>>(kw, wb, convN4);
  gemm_bt256<u16><<<gemmGrid, gblk, 0, stream>>>(mixA, wb, kb, B_ * T_, C_, C_);
  mix_cast_kernel<<<mixGrid, blk, 0, stream>>>(hidden, mv, mixA);
  conv_bf16_kernel<<<convGrid, blk, 0, stream>>>(vw, wb, convN4);
  gemm_bt256<u16><<<gemmGrid, gblk, 0, stream>>>(mixA, wb, vb, B_ * T_, C_, C_);
  mix_cast_kernel<<<mixGrid, blk, 0, stream>>>(hidden, mg, mixA);
  conv_bf16_kernel<<<convGrid, blk, 0, stream>>>(gw, wb, convN4);
  gemm_bt256<u16><<<gemmGrid, gblk, 0, stream>>>(mixA, wb, gb, B_ * T_, C_, C_);

  if (use32) {
    scan_phase1_mfma<64><<<(B_ * H_ * 32) / 2, dim3(128), 0, stream>>>(kb, vb, td, chunks);
    scan_phase2<32, 64><<<2048, blk, 0, stream>>>(state0, td, chunks, state_f);
    scan_phase3_mfma<<<(B_ * H_ * 32) / 4, blk, 0, stream>>>(rb, kb, vb, td, tf, chunks, gb, lnw, lnb, mixA);
  } else {
    scan_phase1<16, 128><<<(B_ * H_ * 16) / 4, blk, 0, stream>>>(kb, vb, td, chunks);
    scan_phase2<16, 128><<<2048, blk, 0, stream>>>(state0, td, chunks, state_f);
    scan_phase3<16, 128><<<(B_ * H_ * 16) / 4, blk, 0, stream>>>(rb, kb, vb, td, tf, chunks, gb, lnw, lnb, mixA);
  }

  conv_bf16_kernel<<<convGrid, blk, 0, stream>>>(ow, wb, convN4);
  gemm_bt256<float><<<gemmGrid, gblk, 0, stream>>>(mixA, wb, out, B_ * T_, C_, C_);
}